// Round 4
// baseline (931.813 us; speedup 1.0000x reference)
//
#include <hip/hip_runtime.h>
#include <hip/hip_bf16.h>
#include <cstdint>

#define BB 4
#define C_IN 512
#define HH 64
#define WW 64
#define HWN 4096
#define QKV_CH 1536
#define PW_GROUPS 192
#define NHEADS2 128
#define TD2 1024
#define EPS_F 1e-5f
#define BN_EPS_F 1e-5f

// ---------------- K1: C[b] = A (MxK) * B[b] (KxN), fp32 I/O, f64 accumulate --
// Tile 64(M) x 128(N), K-step 8, 256 threads, per-thread 4x8 f64 acc.
__global__ __launch_bounds__(256) void gemm_f64acc(
    const float* __restrict__ A, const float* __restrict__ Bm,
    float* __restrict__ Cm, int M, int N, int K)
{
    __shared__ float As[8][64];
    __shared__ float Bs[8][128];
    const int bz = blockIdx.z;
    const float* Bp = Bm + (size_t)bz * K * N;
    float*       Cp = Cm + (size_t)bz * M * N;
    const int m0 = blockIdx.y * 64;
    const int n0 = blockIdx.x * 128;
    const int tid = threadIdx.x;
    const int tx = tid & 15;   // n sub-tile (8 cols)
    const int ty = tid >> 4;   // m sub-tile (4 rows)

    const int a_row = tid >> 1;          // 0..63 for tid<128
    const int a_col = (tid & 1) << 2;
    const int b_row = tid >> 5;          // 0..7
    const int b_col = (tid & 31) << 2;   // 0..124

    const float* Aptr = A + (size_t)(m0 + a_row) * K + a_col;
    const float* Bptr = Bp + (size_t)b_row * N + n0 + b_col;

    float4 av = make_float4(0.f, 0.f, 0.f, 0.f);
    if (tid < 128) av = *reinterpret_cast<const float4*>(Aptr);
    float4 bv = *reinterpret_cast<const float4*>(Bptr);

    double acc[4][8];
#pragma unroll
    for (int i = 0; i < 4; ++i)
#pragma unroll
        for (int j = 0; j < 8; ++j) acc[i][j] = 0.0;

    for (int k0 = 0; k0 < K; k0 += 8) {
        if (tid < 128) {
            As[a_col + 0][a_row] = av.x;
            As[a_col + 1][a_row] = av.y;
            As[a_col + 2][a_row] = av.z;
            As[a_col + 3][a_row] = av.w;
        }
        *reinterpret_cast<float4*>(&Bs[b_row][b_col]) = bv;
        __syncthreads();
        if (k0 + 8 < K) {
            if (tid < 128) av = *reinterpret_cast<const float4*>(Aptr + k0 + 8);
            bv = *reinterpret_cast<const float4*>(Bptr + (size_t)(k0 + 8) * N);
        }
#pragma unroll
        for (int kk = 0; kk < 8; ++kk) {
            float am[4], bn[8];
            *reinterpret_cast<float4*>(&am[0]) = *reinterpret_cast<const float4*>(&As[kk][ty * 4]);
            *reinterpret_cast<float4*>(&bn[0]) = *reinterpret_cast<const float4*>(&Bs[kk][tx * 8]);
            *reinterpret_cast<float4*>(&bn[4]) = *reinterpret_cast<const float4*>(&Bs[kk][tx * 8 + 4]);
#pragma unroll
            for (int i = 0; i < 4; ++i) {
                const double ad = (double)am[i];
#pragma unroll
                for (int j = 0; j < 8; ++j)
                    acc[i][j] = fma(ad, (double)bn[j], acc[i][j]);
            }
        }
        __syncthreads();
    }

#pragma unroll
    for (int i = 0; i < 4; ++i) {
        float* cp = Cp + (size_t)(m0 + ty * 4 + i) * N + n0 + tx * 8;
        float4 o0, o1;
        o0.x = (float)acc[i][0]; o0.y = (float)acc[i][1];
        o0.z = (float)acc[i][2]; o0.w = (float)acc[i][3];
        o1.x = (float)acc[i][4]; o1.y = (float)acc[i][5];
        o1.z = (float)acc[i][6]; o1.w = (float)acc[i][7];
        *reinterpret_cast<float4*>(cp) = o0;
        *reinterpret_cast<float4*>(cp + 4) = o1;
    }
}

// ---------------- K5: tiled fp32 GEMM with split-K-source B + BN epilogue ----
__global__ __launch_bounds__(256) void gemm_f32_epi(
    const float* __restrict__ A,
    const float* __restrict__ B0, const float* __restrict__ B1, int KR0,
    float* __restrict__ Cm, int M, int N, int K,
    const float* __restrict__ g_gamma, const float* __restrict__ g_beta,
    const float* __restrict__ g_mean, const float* __restrict__ g_var)
{
    __shared__ float As[8][128];
    __shared__ float Bs[8][128];
    const int bz = blockIdx.z;
    const float* B0p = B0 + (size_t)bz * KR0 * N;
    const float* B1p = B1 + (size_t)bz * (size_t)(K - KR0) * N - (size_t)KR0 * N;
    float* Cp = Cm + (size_t)bz * M * N;
    const int m0 = blockIdx.y * 128;
    const int n0 = blockIdx.x * 128;
    const int tid = threadIdx.x;
    const int tx = tid & 15;
    const int ty = tid >> 4;

    const int a_row = tid >> 1;
    const int a_col = (tid & 1) << 2;
    const int b_row = tid >> 5;
    const int b_col = (tid & 31) << 2;

    const float* Aptr = A + (size_t)(m0 + a_row) * K + a_col;

    auto loadB = [&](int row) -> float4 {
        const float* base = (row < KR0) ? B0p : B1p;
        return *reinterpret_cast<const float4*>(base + (size_t)row * N + n0 + b_col);
    };

    float4 av = *reinterpret_cast<const float4*>(Aptr);
    float4 bv = loadB(b_row);

    float acc[8][8];
#pragma unroll
    for (int i = 0; i < 8; ++i)
#pragma unroll
        for (int j = 0; j < 8; ++j) acc[i][j] = 0.f;

    for (int k0 = 0; k0 < K; k0 += 8) {
        As[a_col + 0][a_row] = av.x;
        As[a_col + 1][a_row] = av.y;
        As[a_col + 2][a_row] = av.z;
        As[a_col + 3][a_row] = av.w;
        *reinterpret_cast<float4*>(&Bs[b_row][b_col]) = bv;
        __syncthreads();
        if (k0 + 8 < K) {
            av = *reinterpret_cast<const float4*>(Aptr + k0 + 8);
            bv = loadB(k0 + 8 + b_row);
        }
#pragma unroll
        for (int kk = 0; kk < 8; ++kk) {
            float am[8], bn[8];
            *reinterpret_cast<float4*>(&am[0]) = *reinterpret_cast<const float4*>(&As[kk][ty * 8]);
            *reinterpret_cast<float4*>(&am[4]) = *reinterpret_cast<const float4*>(&As[kk][ty * 8 + 4]);
            *reinterpret_cast<float4*>(&bn[0]) = *reinterpret_cast<const float4*>(&Bs[kk][tx * 8]);
            *reinterpret_cast<float4*>(&bn[4]) = *reinterpret_cast<const float4*>(&Bs[kk][tx * 8 + 4]);
#pragma unroll
            for (int i = 0; i < 8; ++i)
#pragma unroll
                for (int j = 0; j < 8; ++j)
                    acc[i][j] = fmaf(am[i], bn[j], acc[i][j]);
        }
        __syncthreads();
    }

#pragma unroll
    for (int i = 0; i < 8; ++i) {
        const int row = m0 + ty * 8 + i;
        const float sc = g_gamma[row] * rsqrtf(g_var[row] + BN_EPS_F);
        const float ad = g_beta[row] - g_mean[row] * sc;
        float* cp = Cp + (size_t)row * N + n0 + tx * 8;
        float4 o0, o1;
        o0.x = acc[i][0] * sc + ad; o0.y = acc[i][1] * sc + ad;
        o0.z = acc[i][2] * sc + ad; o0.w = acc[i][3] * sc + ad;
        o1.x = acc[i][4] * sc + ad; o1.y = acc[i][5] * sc + ad;
        o1.z = acc[i][6] * sc + ad; o1.w = acc[i][7] * sc + ad;
        *reinterpret_cast<float4*>(cp) = o0;
        *reinterpret_cast<float4*>(cp + 4) = o1;
    }
}

// ---------------- K2: fused depthwise 5x5 conv + per-group 8x8 pointwise -----
// f64 accumulation: agg feeds relu(q)/relu(k) whose near-zero sign must match
// the high-precision reference (eps-division amplifies q errors ~kv/eps).
__global__ __launch_bounds__(256) void dw_pw(
    const float* __restrict__ qkv, const float* __restrict__ w_dw,
    const float* __restrict__ w_pw, float* __restrict__ agg)
{
    __shared__ float s_in[8][36][36];
    __shared__ float s_wd[200];
    __shared__ float s_wp[64];
    const int g = blockIdx.y;
    const int b = blockIdx.z;
    const int ty0 = (blockIdx.x >> 1) * 32;
    const int tx0 = (blockIdx.x & 1) * 32;
    const int tid = threadIdx.x;

    for (int idx = tid; idx < 8 * 36 * 36; idx += 256) {
        const int i = idx / 1296;
        const int r = idx - i * 1296;
        const int yy = r / 36;
        const int xx = r - yy * 36;
        const int gy = ty0 + yy - 2, gx = tx0 + xx - 2;
        float v = 0.f;
        if (gy >= 0 && gy < HH && gx >= 0 && gx < WW)
            v = qkv[((size_t)b * QKV_CH + g * 8 + i) * HWN + gy * WW + gx];
        s_in[i][yy][xx] = v;
    }
    if (tid < 200) s_wd[tid] = w_dw[(size_t)g * 200 + tid];
    if (tid >= 200 && tid < 264) s_wp[tid - 200] = w_pw[(size_t)g * 64 + tid - 200];
    __syncthreads();

    const int py = tid >> 3;        // 0..31
    const int xq = (tid & 7) << 2;  // 0..28 step 4

    double outp[8][4];
#pragma unroll
    for (int o = 0; o < 8; ++o)
#pragma unroll
        for (int p = 0; p < 4; ++p) outp[o][p] = 0.0;

#pragma unroll
    for (int i = 0; i < 8; ++i) {
        double dw4[4] = {0.0, 0.0, 0.0, 0.0};
#pragma unroll
        for (int dy = 0; dy < 5; ++dy) {
            const float* row = &s_in[i][py + dy][xq];
            float rr[8];
            *reinterpret_cast<float4*>(&rr[0]) = *reinterpret_cast<const float4*>(&row[0]);
            *reinterpret_cast<float4*>(&rr[4]) = *reinterpret_cast<const float4*>(&row[4]);
#pragma unroll
            for (int dx = 0; dx < 5; ++dx) {
                const double w = (double)s_wd[i * 25 + dy * 5 + dx];
#pragma unroll
                for (int p = 0; p < 4; ++p)
                    dw4[p] = fma((double)rr[p + dx], w, dw4[p]);
            }
        }
#pragma unroll
        for (int o = 0; o < 8; ++o) {
            const double w = (double)s_wp[o * 8 + i];
#pragma unroll
            for (int p = 0; p < 4; ++p) outp[o][p] = fma(dw4[p], w, outp[o][p]);
        }
    }
#pragma unroll
    for (int o = 0; o < 8; ++o) {
        float4 ov;
        ov.x = (float)outp[o][0]; ov.y = (float)outp[o][1];
        ov.z = (float)outp[o][2]; ov.w = (float)outp[o][3];
        *reinterpret_cast<float4*>(
            &agg[((size_t)b * QKV_CH + g * 8 + o) * HWN + (ty0 + py) * WW + tx0 + xq]) = ov;
    }
}

// ---------------- K3: kv[b,h,d,e] = sum_n relu(k)*[v,1] -----------------------
__global__ __launch_bounds__(256) void kv_reduce(
    const float* __restrict__ qkv, const float* __restrict__ agg,
    float* __restrict__ kv)
{
    const int h = blockIdx.x;  // 0..127
    const int b = blockIdx.y;
    const float* src = (h < 64 ? qkv : agg) + ((size_t)b * QKV_CH + (h & 63) * 24) * HWN;
    const int tid = threadIdx.x;

    float acc[72];
#pragma unroll
    for (int j = 0; j < 72; ++j) acc[j] = 0.f;

    for (int n = tid; n < HWN; n += 256) {
        float kk[8], vv[8];
#pragma unroll
        for (int d = 0; d < 8; ++d) kk[d] = fmaxf(src[(size_t)(8 + d) * HWN + n], 0.f);
#pragma unroll
        for (int e = 0; e < 8; ++e) vv[e] = src[(size_t)(16 + e) * HWN + n];
#pragma unroll
        for (int d = 0; d < 8; ++d) {
#pragma unroll
            for (int e = 0; e < 8; ++e) acc[d * 9 + e] = fmaf(kk[d], vv[e], acc[d * 9 + e]);
            acc[d * 9 + 8] += kk[d];
        }
    }

    __shared__ float red[4][72];
    const int lane = tid & 63, wid = tid >> 6;
#pragma unroll
    for (int j = 0; j < 72; ++j) {
        float v = acc[j];
#pragma unroll
        for (int off = 32; off >= 1; off >>= 1) v += __shfl_xor(v, off);
        if (lane == 0) red[wid][j] = v;
    }
    __syncthreads();
    if (tid < 72) {
        const float s = red[0][tid] + red[1][tid] + red[2][tid] + red[3][tid];
        kv[((size_t)b * NHEADS2 + h) * 72 + tid] = s;
    }
}

// ---------------- K4: out = (relu(q)·kv)[:8] / ((relu(q)·kv)[8]+eps) ---------
__global__ __launch_bounds__(256) void attn_out(
    const float* __restrict__ src_all, const float* __restrict__ kv,
    float* __restrict__ dst, int h_off)
{
    const int hl = blockIdx.x;  // 0..63
    const int b = blockIdx.y;
    const float* src = src_all + ((size_t)b * QKV_CH + hl * 24) * HWN;
    __shared__ float skv[72];
    if (threadIdx.x < 72)
        skv[threadIdx.x] = kv[((size_t)b * NHEADS2 + h_off + hl) * 72 + threadIdx.x];
    __syncthreads();
    float* dstp = dst + ((size_t)b * 512 + hl * 8) * HWN;

    for (int n = threadIdx.x; n < HWN; n += 256) {
        float q[8];
#pragma unroll
        for (int d = 0; d < 8; ++d) q[d] = fmaxf(src[(size_t)d * HWN + n], 0.f);
        float num[9];
#pragma unroll
        for (int e = 0; e < 9; ++e) {
            float s = 0.f;
#pragma unroll
            for (int d = 0; d < 8; ++d) s = fmaf(q[d], skv[d * 9 + e], s);
            num[e] = s;
        }
        const float r = 1.f / (num[8] + EPS_F);
#pragma unroll
        for (int e = 0; e < 8; ++e) dstp[(size_t)e * HWN + n] = num[e] * r;
    }
}

// ------------------------------------------------------------------------------
extern "C" void kernel_launch(void* const* d_in, const int* in_sizes, int n_in,
                              void* d_out, int out_size, void* d_ws, size_t ws_size,
                              hipStream_t stream)
{
    const float* x      = (const float*)d_in[0];
    const float* w_qkv  = (const float*)d_in[1];
    const float* w_dw   = (const float*)d_in[2];
    const float* w_pw   = (const float*)d_in[3];
    const float* w_proj = (const float*)d_in[4];
    const float* gamma  = (const float*)d_in[5];
    const float* beta   = (const float*)d_in[6];
    const float* mean   = (const float*)d_in[7];
    const float* var    = (const float*)d_in[8];
    float* out = (float*)d_out;

    // Workspace: kv + qkv + agg + out_tA = 235.0 MB.  out_tB aliases dead qkv.
    float* kv     = (float*)d_ws;                       // B*128*72
    float* qkv    = kv + (size_t)BB * NHEADS2 * 72;     // B*1536*4096
    float* agg    = qkv + (size_t)BB * NHEADS2 * 0 + (size_t)BB * QKV_CH * HWN + ((size_t)BB * NHEADS2 * 72 - (size_t)BB * NHEADS2 * 72); // placeholder arithmetic removed below
    // (clean pointers)
    qkv    = kv + (size_t)BB * NHEADS2 * 72;
    agg    = qkv + (size_t)BB * QKV_CH * HWN;
    float* out_tA = agg + (size_t)BB * QKV_CH * HWN;    // B*512*4096 (heads 0..63)
    float* out_tB = qkv;                                // alias: qkv dead after K4a

    // K1: qkv = w_qkv (1536x512) * x (512x4096) per batch  [f64 accumulate]
    gemm_f64acc<<<dim3(HWN / 128, QKV_CH / 64, BB), 256, 0, stream>>>(
        w_qkv, x, qkv, QKV_CH, HWN, C_IN);

    // K2: fused depthwise conv + pointwise group matmul -> agg [f64 accumulate]
    dw_pw<<<dim3(4, PW_GROUPS, BB), 256, 0, stream>>>(qkv, w_dw, w_pw, agg);

    // K3: kv reduction (reads qkv + agg)
    kv_reduce<<<dim3(NHEADS2, BB), 256, 0, stream>>>(qkv, agg, kv);

    // K4a: heads 0..63 (reads qkv) -> out_tA.  K4b: heads 64..127 (reads agg)
    // -> out_tB which ALIASES qkv (qkv dead once K4a completes; same stream).
    attn_out<<<dim3(64, BB), 256, 0, stream>>>(qkv, kv, out_tA, 0);
    attn_out<<<dim3(64, BB), 256, 0, stream>>>(agg, kv, out_tB, 64);

    // K5: y = w_proj (512x1024) * [out_tA; out_tB] + BN affine
    gemm_f32_epi<<<dim3(HWN / 128, C_IN / 128, BB), 256, 0, stream>>>(
        w_proj, out_tA, out_tB, 512, out, C_IN, HWN, TD2,
        gamma, beta, mean, var);
}